// Round 13
// baseline (551.790 us; speedup 1.0000x reference)
//
#include <hip/hip_runtime.h>
#include <hip/hip_bf16.h>
#include <cstdint>
#include <cstddef>

typedef __attribute__((ext_vector_type(8))) short short8;
typedef __attribute__((ext_vector_type(4))) float f32x4;
typedef unsigned short u16;

static __device__ __forceinline__ u16 f2bf(float f) {
  __hip_bfloat16 h = __float2bfloat16(f);
  return *reinterpret_cast<u16*>(&h);
}

static __device__ __forceinline__ void gload16(const void* g, void* l) {
  __builtin_amdgcn_global_load_lds(
      (const __attribute__((address_space(1))) void*)g,
      (__attribute__((address_space(3))) void*)l, 16, 0, 0);
}

// ---------------- prep kernels ----------------

__global__ void cast4_k(const float* __restrict__ a, const float* __restrict__ b,
                        const float* __restrict__ c, const float* __restrict__ d,
                        u16* __restrict__ oa, u16* __restrict__ ob,
                        u16* __restrict__ oc, u16* __restrict__ od) {
  const int which = blockIdx.y;
  const float* src = (which == 0) ? a : (which == 1) ? b : (which == 2) ? c : d;
  u16* dst = (which == 0) ? oa : (which == 1) ? ob : (which == 2) ? oc : od;
  int i = blockIdx.x * 256 + threadIdx.x;
  float4 v = ((const float4*)src)[i];
  union { u16 u[4]; uint2 p; } r;
  r.u[0] = f2bf(v.x); r.u[1] = f2bf(v.y); r.u[2] = f2bf(v.z); r.u[3] = f2bf(v.w);
  ((uint2*)dst)[i] = r.p;
}

// in_t_pad[(b*34 + y+1)*34 + x+1][i] = bf16( concat(x1,x2)[b][i][y*32+x] )
__global__ void build_pad(const float* __restrict__ x1, const float* __restrict__ x2,
                          u16* __restrict__ in_t_pad, u16* __restrict__ x1b) {
  __shared__ float tile[64][65];
  const int it = blockIdx.x;
  const int st = blockIdx.y;
  const int b  = blockIdx.z;
  const int i0 = it * 64, s0 = st * 64;
  const bool isx1 = (i0 < 1024);
  const float* src = isx1
      ? x1 + ((size_t)b * 1024 + i0) * 1024
      : x2 + ((size_t)b * 1024 + (i0 - 1024)) * 1024;
  const int t = threadIdx.x;
  #pragma unroll
  for (int jj = 0; jj < 16; ++jj) {
    int idx = jj * 256 + t;
    int ii = idx >> 6, si = idx & 63;
    float v = src[(size_t)ii * 1024 + s0 + si];
    tile[ii][si] = v;
    if (isx1)
      x1b[((size_t)b * 1024 + i0 + ii) * 1024 + s0 + si] = f2bf(v);
  }
  __syncthreads();
  #pragma unroll
  for (int jj = 0; jj < 16; ++jj) {
    int idx = jj * 256 + t;
    int si = idx >> 6, ii = idx & 63;
    const int s = s0 + si;
    const int prow = (b * 34 + (s >> 5) + 1) * 34 + (s & 31) + 1;
    in_t_pad[(size_t)prow * 2048 + i0 + ii] = f2bf(tile[ii][si]);
  }
}

// Wp[q][o][i] = bf16( conv_w[o][i][q] ),  q = ky*3+kx
__global__ void pack_wp(const float* __restrict__ cw, u16* __restrict__ Wp) {
  __shared__ float sb[2304];
  const int blk = blockIdx.x;
  const int t = threadIdx.x;
  const size_t base = (size_t)blk * 2304;
  #pragma unroll
  for (int jj = 0; jj < 9; ++jj) sb[jj * 256 + t] = cw[base + jj * 256 + t];
  __syncthreads();
  const int p = blk * 256 + t;
  #pragma unroll
  for (int q = 0; q < 9; ++q)
    Wp[(size_t)q * 2097152 + p] = f2bf(sb[t * 9 + q]);
}

// split-K combine: xc[b][o][s] = bf16(p0 + p1 + bias[o]); p is [kz][b*1024+s][o] f32
__global__ void addc_k(const float* __restrict__ p, const float* __restrict__ bias,
                       u16* __restrict__ xc) {
  __shared__ float tile[64][65];
  const int st = blockIdx.x;
  const int ot = blockIdx.y;
  const int b  = blockIdx.z;
  const int s0 = st * 64, o0 = ot * 64;
  const int t = threadIdx.x;
  const float* p1 = p + 8388608;
  #pragma unroll
  for (int jj = 0; jj < 16; ++jj) {
    int idx = jj * 256 + t;
    int si = idx >> 6, oi = idx & 63;
    const size_t m = ((size_t)b * 1024 + s0 + si) * 1024 + o0 + oi;
    tile[si][oi] = p[m] + p1[m] + bias[o0 + oi];
  }
  __syncthreads();
  #pragma unroll
  for (int jj = 0; jj < 16; ++jj) {
    int idx = jj * 256 + t;
    int oi = idx >> 6, si = idx & 63;
    xc[((size_t)b * 1024 + o0 + oi) * 1024 + s0 + si] = f2bf(tile[si][oi]);
  }
}

enum { GM_PLAIN = 0, GM_PROJ = 2 };

// ---------------- conv GEMM: halo reuse + av-prefetch pipeline ----------------
// 256x256 block, 4 waves, wave tile 128x128. A-halo stable across the 9 planes of
// a chunk -> read av(q+1) BEFORE plane q's MFMA cluster so the ds_reads drain
// under the MFMAs (static ping-pong avb[q&1], q-loop fully unrolled).
__global__ __launch_bounds__(256, 1)
void conv11_k(const u16* __restrict__ Ap, const u16* __restrict__ B,
              float* __restrict__ Cf) {
  __shared__ u16 lds[2 * 12288 + 3 * 8192];
  const int tid = threadIdx.x;
  const int lane = tid & 63, w = tid >> 6;
  const int l15 = lane & 15, l4 = lane >> 4;

  const int bid = blockIdx.x;
  const int lb = (bid & 7) * 32 + (bid >> 3);
  const int kz = lb >> 7;
  const int tile = lb & 127;
  const int tm = tile >> 2, tn = tile & 3;
  const int row0 = tm * 256, col0 = tn * 256;
  const int b = tm >> 2;
  const int y0 = (tm & 3) * 8;
  const int hb = (b * 34 + y0) * 34;
  const int wr = (w >> 1) * 128, wc = (w & 1) * 128;
  const int chbase = kz * 1024;

  int pr[8];
  #pragma unroll
  for (int mi = 0; mi < 8; ++mi) {
    const int m = row0 + wr + mi * 16 + l15;
    const int y = (m >> 5) & 31, x = m & 31;
    pr[mi] = (y - y0 + 1) * 34 + x + 1;
  }

  const int srow = tid >> 2;
  const int sgc = tid & 3;

  f32x4 acc[8][8];
  #pragma unroll
  for (int i = 0; i < 8; ++i)
    #pragma unroll
    for (int jj = 0; jj < 8; ++jj)
      acc[i][jj] = (f32x4){0.f, 0.f, 0.f, 0.f};

  auto stageHalo = [&](int cc, int half) {
    u16* dst = lds + half * 12288;
    #pragma unroll
    for (int rnd = 0; rnd < 6; ++rnd) {
      const int row = rnd * 64 + srow;
      const int g = sgc ^ ((row >> 1) & 3);
      const u16* src = Ap + (size_t)(hb + row) * 2048 + chbase + cc * 32 + g * 8;
      gload16(src, dst + (size_t)(rnd * 256 + tid) * 8);
    }
  };
  auto stageB = [&](int cc, int q) {
    u16* dst = lds + 24576 + (q % 3) * 8192;
    #pragma unroll
    for (int rnd = 0; rnd < 4; ++rnd) {
      const int r = rnd * 64 + srow;
      const int g = sgc ^ ((r >> 1) & 3);
      const u16* src = B + ((size_t)q << 21) + (size_t)(col0 + r) * 2048
                       + chbase + cc * 32 + g * 8;
      gload16(src, dst + (size_t)(rnd * 256 + tid) * 8);
    }
  };

  constexpr int ddt[9] = {-35, -34, -33, -1, 0, 1, 33, 34, 35};
  constexpr int NC = 32;

  stageHalo(0, 0);
  stageHalo(1, 1);
  stageB(0, 0);
  stageB(0, 1);

  short8 avb[2][8];

  for (int cc = 0; cc < NC; ++cc) {
    const u16* hcur = lds + (cc & 1) * 12288;
    const bool interior = (cc >= 1 && cc <= NC - 2);
    #pragma unroll
    for (int q = 0; q < 9; ++q) {
      if ((q == 1 || q == 2) && interior) {
        asm volatile("s_waitcnt vmcnt(10)" ::: "memory");
      } else if (q == 8 && cc == NC - 1) {
        asm volatile("s_waitcnt vmcnt(0)" ::: "memory");
      } else {
        asm volatile("s_waitcnt vmcnt(4)" ::: "memory");
      }
      __builtin_amdgcn_s_barrier();
      {
        const int gp2 = cc * 9 + q + 2;
        if (gp2 <= NC * 9 - 1) {
          int qS = q + 2, ccS = cc;
          if (qS >= 9) { qS -= 9; ccS += 1; }
          stageB(ccS, qS);
        }
        if (q == 0 && cc >= 1 && cc <= NC - 2)
          stageHalo(cc + 1, (cc + 1) & 1);
      }
      {
        const u16* bq = lds + 24576 + (q % 3) * 8192;
        // first plane of the chunk: load its A frags directly
        if (q == 0) {
          #pragma unroll
          for (int mi = 0; mi < 8; ++mi) {
            const int hr = pr[mi] + ddt[0];
            const int g = l4 ^ ((hr >> 1) & 3);
            avb[0][mi] = *(const short8*)(hcur + hr * 32 + g * 8);
          }
        }
        short8 bv[8];
        #pragma unroll
        for (int ni = 0; ni < 8; ++ni) {
          const int r = wc + ni * 16 + l15;
          const int g = l4 ^ ((r >> 1) & 3);
          bv[ni] = *(const short8*)(bq + r * 32 + g * 8);
        }
        // prefetch next plane's A frags (halo stable within chunk) -> drains
        // under this plane's MFMA cluster
        if (q < 8) {
          #pragma unroll
          for (int mi = 0; mi < 8; ++mi) {
            const int hr = pr[mi] + ddt[q + 1];
            const int g = l4 ^ ((hr >> 1) & 3);
            avb[(q + 1) & 1][mi] = *(const short8*)(hcur + hr * 32 + g * 8);
          }
        }
        __builtin_amdgcn_s_setprio(1);
        #pragma unroll
        for (int mi = 0; mi < 8; ++mi)
          #pragma unroll
          for (int ni = 0; ni < 8; ++ni)
            acc[mi][ni] = __builtin_amdgcn_mfma_f32_16x16x32_bf16(avb[q & 1][mi], bv[ni], acc[mi][ni], 0, 0, 0);
        __builtin_amdgcn_s_setprio(0);
      }
    }
  }

  #pragma unroll
  for (int mi = 0; mi < 8; ++mi) {
    #pragma unroll
    for (int ni = 0; ni < 8; ++ni) {
      #pragma unroll
      for (int j = 0; j < 4; ++j) {
        const int grow = row0 + wr + mi * 16 + l4 * 4 + j;
        const int gcol = col0 + wc + ni * 16 + l15;
        Cf[(size_t)kz * 8388608 + ((size_t)grow << 10) + gcol] = acc[mi][ni][j];
      }
    }
  }
}

// ---------------- GEMM A: 256x128 tile, BK=64 (proj only) ----------------
template<int MODE>
__global__ __launch_bounds__(512, 2)
void gemm3_k(const u16* __restrict__ A, const u16* __restrict__ B,
             u16* __restrict__ Cb, float* __restrict__ Cf,
             const float* __restrict__ bias, const float* __restrict__ resid,
             int Ktot, int ntn_sh) {
  __shared__ u16 lds[3 * 24576];
  const int tid = threadIdx.x;
  const int lane = tid & 63;
  const int w = tid >> 6;
  const int l15 = lane & 15, l4 = lane >> 4;

  const int nwg = gridDim.x;
  const int bid = blockIdx.x;
  const int lb = (bid & 7) * (nwg >> 3) + (bid >> 3);
  const int tm = lb >> ntn_sh;
  const int tn = lb & ((1 << ntn_sh) - 1);
  const int row0 = tm * 256, col0 = tn * 128;
  const int wr = (w >> 1) * 64, wc = (w & 1) * 64;

  const int sr = w * 8 + (lane >> 3);
  const int pp = (lane & 7) ^ (lane >> 3);

  f32x4 acc[4][4];
  #pragma unroll
  for (int i = 0; i < 4; ++i)
    #pragma unroll
    for (int jj = 0; jj < 4; ++jj)
      acc[i][jj] = (f32x4){0.f, 0.f, 0.f, 0.f};

  const int nK = Ktot >> 6;

  auto stage = [&](int kt, u16* buf) {
    u16* da = buf + (size_t)w * 512;
    u16* db = buf + 16384 + (size_t)w * 512;
    const int k0 = kt << 6;
    #pragma unroll
    for (int u = 0; u < 4; ++u) {
      const u16* ga = A + (size_t)(row0 + u * 64 + sr) * Ktot + k0 + pp * 8;
      gload16(ga, da + u * 4096);
    }
    #pragma unroll
    for (int u = 0; u < 2; ++u) {
      const u16* gb = B + (size_t)(col0 + u * 64 + sr) * Ktot + k0 + pp * 8;
      gload16(gb, db + u * 4096);
    }
  };

  auto compute = [&](const u16* buf) {
    const char* Ar = (const char*)buf;
    const char* Br = (const char*)(buf + 16384);
    #pragma unroll
    for (int ks = 0; ks < 2; ++ks) {
      const int bcol = ((ks << 6) + (l4 << 4)) ^ ((l15 & 7) << 4);
      short8 av[4], bv[4];
      #pragma unroll
      for (int mi = 0; mi < 4; ++mi)
        av[mi] = *(const short8*)(Ar + (wr + mi * 16 + l15) * 128 + bcol);
      #pragma unroll
      for (int ni = 0; ni < 4; ++ni)
        bv[ni] = *(const short8*)(Br + (wc + ni * 16 + l15) * 128 + bcol);
      __builtin_amdgcn_s_setprio(1);
      #pragma unroll
      for (int mi = 0; mi < 4; ++mi)
        #pragma unroll
        for (int ni = 0; ni < 4; ++ni)
          acc[mi][ni] = __builtin_amdgcn_mfma_f32_16x16x32_bf16(av[mi], bv[ni], acc[mi][ni], 0, 0, 0);
      __builtin_amdgcn_s_setprio(0);
    }
  };

  u16* pb0 = lds;
  u16* pb1 = lds + 24576;
  u16* pb2 = lds + 49152;

  stage(0, pb0);
  stage(1, pb1);
  for (int t = 0; t < nK; ++t) {
    if (t + 1 < nK) {
      asm volatile("s_waitcnt vmcnt(6)" ::: "memory");
    } else {
      asm volatile("s_waitcnt vmcnt(0)" ::: "memory");
    }
    __builtin_amdgcn_s_barrier();
    if (t + 2 < nK) stage(t + 2, pb2);
    compute(pb0);
    u16* tmp = pb0; pb0 = pb1; pb1 = pb2; pb2 = tmp;
  }

  #pragma unroll
  for (int mi = 0; mi < 4; ++mi) {
    #pragma unroll
    for (int ni = 0; ni < 4; ++ni) {
      #pragma unroll
      for (int j = 0; j < 4; ++j) {
        const int grow = row0 + wr + mi * 16 + l4 * 4 + j;
        const int gcol = col0 + wc + ni * 16 + l15;
        const float v = acc[mi][ni][j];
        if constexpr (MODE == GM_PLAIN) {
          Cb[((size_t)grow << 10) + gcol] = f2bf(v);
        } else if constexpr (MODE == GM_PROJ) {
          const size_t o = ((size_t)grow << 10) + gcol;
          Cf[o] = v + bias[gcol] + resid[o];
        }
      }
    }
  }
}

// ---------------- fused QKV GEMM: 768 blocks (sel 0=Q,1=K,2=V), BK=32, 8 waves ----------------
// V blocks write Vt via LDS transpose bounce (coalesced).
__global__ __launch_bounds__(512, 4)
void qkv_k(const u16* __restrict__ Ax1, const u16* __restrict__ Axc,
           const u16* __restrict__ Wq, const u16* __restrict__ Wk,
           const u16* __restrict__ Wv,
           u16* __restrict__ Qb, u16* __restrict__ Kb, u16* __restrict__ Vtb) {
  __shared__ u16 lds[3 * 12288];
  const int tid = threadIdx.x;
  const int lane = tid & 63;
  const int w = tid >> 6;
  const int l15 = lane & 15, l4 = lane >> 4;

  const int bid = blockIdx.x;             // grid = 768
  const int lb = (bid & 7) * 96 + (bid >> 3);
  const int sel = lb >> 8;                // 0=Q, 1=K, 2=V
  const int sub = lb & 255;
  const int tm = sub >> 3, tn = sub & 7;
  const int row0 = tm * 256, col0 = tn * 128;
  const int wr = (w >> 1) * 64, wc = (w & 1) * 64;

  const u16* A = (sel == 0) ? Ax1 : Axc;
  const u16* B = (sel == 0) ? Wq : (sel == 1) ? Wk : Wv;

  const int str = tid >> 2;
  const int sgc = tid & 3;

  f32x4 acc[4][4];
  #pragma unroll
  for (int i = 0; i < 4; ++i)
    #pragma unroll
    for (int jj = 0; jj < 4; ++jj)
      acc[i][jj] = (f32x4){0.f, 0.f, 0.f, 0.f};

  constexpr int Ktot = 1024;
  const int nKt = Ktot >> 5;

  auto stage = [&](int kt, u16* buf) {
    const int k0 = kt << 5;
    #pragma unroll
    for (int u = 0; u < 2; ++u) {
      const int r = u * 128 + str;
      const int swz = sgc ^ ((r >> 1) & 3);
      const u16* ga = A + (size_t)(row0 + r) * Ktot + k0 + swz * 8;
      gload16(ga, buf + ((size_t)u * 512 + tid) * 8);
    }
    {
      const int swz = sgc ^ ((str >> 1) & 3);
      const u16* gb = B + (size_t)(col0 + str) * Ktot + k0 + swz * 8;
      gload16(gb, buf + 8192 + (size_t)tid * 8);
    }
  };

  auto compute = [&](const u16* buf) {
    short8 av[4], bv[4];
    #pragma unroll
    for (int mi = 0; mi < 4; ++mi) {
      const int row = wr + mi * 16 + l15;
      const int g = l4 ^ ((row >> 1) & 3);
      av[mi] = *(const short8*)(buf + row * 32 + g * 8);
    }
    #pragma unroll
    for (int ni = 0; ni < 4; ++ni) {
      const int row = wc + ni * 16 + l15;
      const int g = l4 ^ ((row >> 1) & 3);
      bv[ni] = *(const short8*)(buf + 8192 + row * 32 + g * 8);
    }
    __builtin_amdgcn_s_setprio(1);
    #pragma unroll
    for (int mi = 0; mi < 4; ++mi)
      #pragma unroll
      for (int ni = 0; ni < 4; ++ni)
        acc[mi][ni] = __builtin_amdgcn_mfma_f32_16x16x32_bf16(av[mi], bv[ni], acc[mi][ni], 0, 0, 0);
    __builtin_amdgcn_s_setprio(0);
  };

  u16* pb0 = lds;
  u16* pb1 = lds + 12288;
  u16* pb2 = lds + 24576;

  stage(0, pb0);
  stage(1, pb1);
  for (int t = 0; t < nKt; ++t) {
    if (t + 1 < nKt) {
      asm volatile("s_waitcnt vmcnt(3)" ::: "memory");
    } else {
      asm volatile("s_waitcnt vmcnt(0)" ::: "memory");
    }
    __builtin_amdgcn_s_barrier();
    if (t + 2 < nKt) stage(t + 2, pb2);
    compute(pb0);
    u16* tmp = pb0; pb0 = pb1; pb1 = pb2; pb2 = tmp;
  }

  if (sel < 2) {
    u16* Cb = (sel == 0) ? Qb : Kb;
    #pragma unroll
    for (int mi = 0; mi < 4; ++mi)
      #pragma unroll
      for (int ni = 0; ni < 4; ++ni)
        #pragma unroll
        for (int j = 0; j < 4; ++j) {
          const int grow = row0 + wr + mi * 16 + l4 * 4 + j;
          const int gcol = col0 + wc + ni * 16 + l15;
          Cb[((size_t)grow << 10) + gcol] = f2bf(acc[mi][ni][j]);
        }
  } else {
    // V block: transpose 256x128 via LDS (padded rows), write Vt coalesced.
    const int h = tn;
    const int bb = row0 >> 10;
    u16* tb = lds;
    #pragma unroll
    for (int chunk = 0; chunk < 4; ++chunk) {
      __syncthreads();
      if ((w >> 1) == chunk) {
        #pragma unroll
        for (int mi = 0; mi < 4; ++mi)
          #pragma unroll
          for (int ni = 0; ni < 4; ++ni)
            #pragma unroll
            for (int j = 0; j < 4; ++j) {
              const int d = wc + ni * 16 + l15;
              const int t = mi * 16 + l4 * 4 + j;
              tb[d * 66 + t] = f2bf(acc[mi][ni][j]);
            }
      }
      __syncthreads();
      {
        const int r = tid >> 2;
        const int c0 = (tid & 3) * 16;
        const int tok = (row0 & 1023) + chunk * 64 + c0;
        uint4 v0 = *(const uint4*)(tb + r * 66 + c0);
        uint4 v1 = *(const uint4*)(tb + r * 66 + c0 + 8);
        u16* dst = Vtb + (((size_t)((bb * 8 + h) * 128 + r)) << 10) + tok;
        *(uint4*)dst = v0;
        *(uint4*)(dst + 8) = v1;
      }
    }
  }
}

// ---------------- flash attention (double-buffered, KV-locality XCD remap) ----------------
__global__ __launch_bounds__(256, 2)
void attn2_k(const u16* __restrict__ Q, const u16* __restrict__ K,
             const u16* __restrict__ Vt, u16* __restrict__ O) {
  __shared__ u16 Ks[2][64 * 128];
  __shared__ u16 Vs[2][128 * 64];
  __shared__ u16 Plds[4][16 * 72];
  const int bid = blockIdx.x;                 // grid = 1024
  const int lb = (bid & 7) * 128 + (bid >> 3);
  const int bh = lb >> 4;
  const int mtile = lb & 15;
  const int b = bh >> 3, h = bh & 7;
  const int tid = threadIdx.x, lane = tid & 63, w = tid >> 6;
  const int l15 = lane & 15, l4 = lane >> 4;

  short8 qf[4];
  {
    const int qrow = b * 1024 + mtile * 64 + w * 16 + l15;
    const u16* qb = Q + ((size_t)qrow << 10) + h * 128;
    #pragma unroll
    for (int kk = 0; kk < 4; ++kk)
      qf[kk] = *(const short8*)(qb + kk * 32 + l4 * 8);
  }

  f32x4 o[8];
  #pragma unroll
  for (int db = 0; db < 8; ++db) o[db] = (f32x4){0.f, 0.f, 0.f, 0.f};
  float mrow[4], lrow[4];
  #pragma unroll
  for (int j = 0; j < 4; ++j) { mrow[j] = -1e30f; lrow[j] = 0.f; }
  const float scale = 0.08838834764831845f;

  auto stageKV = [&](int kt, int half) {
    #pragma unroll
    for (int j = 0; j < 4; ++j) {
      const int c = (j * 4 + w) * 64 + lane;
      const int r = c >> 4;
      const int coff = (((c & 15) ^ (r & 7)) << 3);
      const u16* gp = K + ((size_t)(b * 1024 + kt * 64 + r) << 10) + h * 128 + coff;
      gload16(gp, (void*)(Ks[half] + (j * 4 + w) * 512));
    }
    #pragma unroll
    for (int j = 0; j < 4; ++j) {
      const int c = (j * 4 + w) * 64 + lane;
      const int r = c >> 3;
      const int coff = (((c & 7) ^ (r & 7)) << 3);
      const u16* gp = Vt + ((size_t)((b * 8 + h) * 128 + r) << 10) + kt * 64 + coff;
      gload16(gp, (void*)(Vs[half] + (j * 4 + w) * 512));
    }
  };

  stageKV(0, 0);
  for (int kt = 0; kt < 16; ++kt) {
    const int cur = kt & 1;
    asm volatile("s_waitcnt vmcnt(0)" ::: "memory");
    __builtin_amdgcn_s_barrier();
    if (kt + 1 < 16) stageKV(kt + 1, cur ^ 1);

    const u16* ks_ = Ks[cur];
    const u16* vs_ = Vs[cur];
    f32x4 s[4];
    #pragma unroll
    for (int cb = 0; cb < 4; ++cb) {
      s[cb] = (f32x4){0.f, 0.f, 0.f, 0.f};
      #pragma unroll
      for (int kk = 0; kk < 4; ++kk) {
        const int col = (kk * 32 + l4 * 8) ^ ((l15 & 7) << 3);
        short8 bK = *(const short8*)(ks_ + (cb * 16 + l15) * 128 + col);
        __builtin_amdgcn_s_setprio(1);
        s[cb] = __builtin_amdgcn_mfma_f32_16x16x32_bf16(qf[kk], bK, s[cb], 0, 0, 0);
        __builtin_amdgcn_s_setprio(0);
      }
    }
    #pragma unroll
    for (int cb = 0; cb < 4; ++cb) {
      s[cb][0] *= scale; s[cb][1] *= scale; s[cb][2] *= scale; s[cb][3] *= scale;
    }
    #pragma unroll
    for (int j = 0; j < 4; ++j) {
      float mx = fmaxf(fmaxf(s[0][j], s[1][j]), fmaxf(s[2][j], s[3][j]));
      #pragma unroll
      for (int off = 8; off >= 1; off >>= 1)
        mx = fmaxf(mx, __shfl_xor(mx, off, 64));
      const float mn = fmaxf(mrow[j], mx);
      const float fac = __expf(mrow[j] - mn);
      mrow[j] = mn;
      float rs = 0.f;
      #pragma unroll
      for (int cb = 0; cb < 4; ++cb) {
        const float p = __expf(s[cb][j] - mn);
        s[cb][j] = p;
        rs += p;
      }
      #pragma unroll
      for (int off = 8; off >= 1; off >>= 1)
        rs += __shfl_xor(rs, off, 64);
      lrow[j] = lrow[j] * fac + rs;
      #pragma unroll
      for (int db = 0; db < 8; ++db) o[db][j] *= fac;
    }
    u16* pl = Plds[w];
    #pragma unroll
    for (int cb = 0; cb < 4; ++cb)
      #pragma unroll
      for (int j = 0; j < 4; ++j)
        pl[(l4 * 4 + j) * 72 + cb * 16 + l15] = f2bf(s[cb][j]);
    asm volatile("s_waitcnt lgkmcnt(0)" ::: "memory");
    __builtin_amdgcn_sched_barrier(0);
    short8 ap[2];
    #pragma unroll
    for (int ks2 = 0; ks2 < 2; ++ks2)
      ap[ks2] = *(const short8*)(pl + l15 * 72 + ks2 * 32 + l4 * 8);
    #pragma unroll
    for (int db = 0; db < 8; ++db) {
      #pragma unroll
      for (int ks2 = 0; ks2 < 2; ++ks2) {
        const int col = (ks2 * 32 + l4 * 8) ^ ((l15 & 7) << 3);
        short8 bV = *(const short8*)(vs_ + (db * 16 + l15) * 64 + col);
        __builtin_amdgcn_s_setprio(1);
        o[db] = __builtin_amdgcn_mfma_f32_16x16x32_bf16(ap[ks2], bV, o[db], 0, 0, 0);
        __builtin_amdgcn_s_setprio(0);
      }
    }
  }
  #pragma unroll
  for (int db = 0; db < 8; ++db) {
    #pragma unroll
    for (int j = 0; j < 4; ++j) {
      const int grow = b * 1024 + mtile * 64 + w * 16 + l4 * 4 + j;
      const int gcol = h * 128 + db * 16 + l15;
      O[((size_t)grow << 10) + gcol] = f2bf(o[db][j] / lrow[j]);
    }
  }
}

// ---------------- launch ----------------

extern "C" void kernel_launch(void* const* d_in, const int* in_sizes, int n_in,
                              void* d_out, int out_size, void* d_ws, size_t ws_size,
                              hipStream_t stream) {
  const float* x1     = (const float*)d_in[0];
  const float* x2     = (const float*)d_in[1];
  const float* conv_w = (const float*)d_in[2];
  const float* conv_b = (const float*)d_in[3];
  const float* wq     = (const float*)d_in[4];
  const float* wk     = (const float*)d_in[5];
  const float* wv     = (const float*)d_in[6];
  const float* proj_w = (const float*)d_in[7];
  const float* proj_b = (const float*)d_in[8];
  float* out = (float*)d_out;

  char* ws = (char*)d_ws;
  size_t off = 0;
  auto alloc = [&](size_t bytes) -> void* {
    void* p = ws + off;
    off += (bytes + 255) & ~(size_t)255;
    return p;
  };
  u16* x1b  = (u16*)alloc(8192ULL * 1024 * 2);
  u16* in_t_pad = (u16*)alloc((9248ULL + 96) * 2048 * 2);
  const size_t pad_bytes = 9248ULL * 2048 * 2;
  u16* Wp   = (u16*)alloc(9ULL * 2097152 * 2);
  u16* wqb  = (u16*)alloc(1048576ULL * 2);
  u16* wkb  = (u16*)alloc(1048576ULL * 2);
  u16* wvb  = (u16*)alloc(1048576ULL * 2);
  u16* pjb  = (u16*)alloc(1048576ULL * 2);
  u16* xc   = (u16*)alloc(8192ULL * 1024 * 2);
  u16* Qb   = (u16*)alloc(8192ULL * 1024 * 2);
  u16* Kb   = (u16*)alloc(8192ULL * 1024 * 2);
  u16* Vtb  = (u16*)alloc(8192ULL * 1024 * 2);
  u16* Ob   = (u16*)alloc(8192ULL * 1024 * 2);
  float* pConv = (float*)Qb;   // split-K f32 partials alias Qb..Ob

  // prep
  (void)hipMemsetAsync(in_t_pad, 0, pad_bytes + 96ULL * 2048 * 2, stream);
  cast4_k<<<dim3(1024, 4), 256, 0, stream>>>(wq, wk, wv, proj_w, wqb, wkb, wvb, pjb);
  build_pad<<<dim3(32, 16, 8), 256, 0, stream>>>(x1, x2, in_t_pad, x1b);
  pack_wp<<<8192, 256, 0, stream>>>(conv_w, Wp);

  // conv: halo-reuse + av-prefetch pipeline, split-K x2
  conv11_k<<<256, 256, 0, stream>>>(in_t_pad, Wp, pConv);
  addc_k<<<dim3(16, 16, 8), 256, 0, stream>>>(pConv, conv_b, xc);
  // fused Q + K + V (768 blocks; V transposed via LDS bounce)
  qkv_k<<<768, 512, 0, stream>>>(x1b, xc, wqb, wkb, wvb, Qb, Kb, Vtb);
  // attention (1D grid, KV-locality remap)
  attn2_k<<<1024, 256, 0, stream>>>(Qb, Kb, Vtb, Ob);
  // projection + bias + residual
  gemm3_k<GM_PROJ><<<256, 512, 0, stream>>>(Ob, pjb, nullptr, out, proj_b, x1, 1024, 3);
}

// Round 14
// 497.460 us; speedup vs baseline: 1.1092x; 1.1092x over previous
//
#include <hip/hip_runtime.h>
#include <hip/hip_bf16.h>
#include <cstdint>
#include <cstddef>

typedef __attribute__((ext_vector_type(8))) short short8;
typedef __attribute__((ext_vector_type(4))) float f32x4;
typedef unsigned short u16;

static __device__ __forceinline__ u16 f2bf(float f) {
  __hip_bfloat16 h = __float2bfloat16(f);
  return *reinterpret_cast<u16*>(&h);
}

static __device__ __forceinline__ void gload16(const void* g, void* l) {
  __builtin_amdgcn_global_load_lds(
      (const __attribute__((address_space(1))) void*)g,
      (__attribute__((address_space(3))) void*)l, 16, 0, 0);
}

// ---------------- prep kernels ----------------

__global__ void cast4_k(const float* __restrict__ a, const float* __restrict__ b,
                        const float* __restrict__ c, const float* __restrict__ d,
                        u16* __restrict__ oa, u16* __restrict__ ob,
                        u16* __restrict__ oc, u16* __restrict__ od) {
  const int which = blockIdx.y;
  const float* src = (which == 0) ? a : (which == 1) ? b : (which == 2) ? c : d;
  u16* dst = (which == 0) ? oa : (which == 1) ? ob : (which == 2) ? oc : od;
  int i = blockIdx.x * 256 + threadIdx.x;
  float4 v = ((const float4*)src)[i];
  union { u16 u[4]; uint2 p; } r;
  r.u[0] = f2bf(v.x); r.u[1] = f2bf(v.y); r.u[2] = f2bf(v.z); r.u[3] = f2bf(v.w);
  ((uint2*)dst)[i] = r.p;
}

// in_t_pad[(b*34 + y+1)*34 + x+1][i] = bf16( concat(x1,x2)[b][i][y*32+x] )
__global__ void build_pad(const float* __restrict__ x1, const float* __restrict__ x2,
                          u16* __restrict__ in_t_pad, u16* __restrict__ x1b) {
  __shared__ float tile[64][65];
  const int it = blockIdx.x;
  const int st = blockIdx.y;
  const int b  = blockIdx.z;
  const int i0 = it * 64, s0 = st * 64;
  const bool isx1 = (i0 < 1024);
  const float* src = isx1
      ? x1 + ((size_t)b * 1024 + i0) * 1024
      : x2 + ((size_t)b * 1024 + (i0 - 1024)) * 1024;
  const int t = threadIdx.x;
  #pragma unroll
  for (int jj = 0; jj < 16; ++jj) {
    int idx = jj * 256 + t;
    int ii = idx >> 6, si = idx & 63;
    float v = src[(size_t)ii * 1024 + s0 + si];
    tile[ii][si] = v;
    if (isx1)
      x1b[((size_t)b * 1024 + i0 + ii) * 1024 + s0 + si] = f2bf(v);
  }
  __syncthreads();
  #pragma unroll
  for (int jj = 0; jj < 16; ++jj) {
    int idx = jj * 256 + t;
    int si = idx >> 6, ii = idx & 63;
    const int s = s0 + si;
    const int prow = (b * 34 + (s >> 5) + 1) * 34 + (s & 31) + 1;
    in_t_pad[(size_t)prow * 2048 + i0 + ii] = f2bf(tile[ii][si]);
  }
}

// Wp[q][o][i] = bf16( conv_w[o][i][q] ),  q = ky*3+kx
__global__ void pack_wp(const float* __restrict__ cw, u16* __restrict__ Wp) {
  __shared__ float sb[2304];
  const int blk = blockIdx.x;
  const int t = threadIdx.x;
  const size_t base = (size_t)blk * 2304;
  #pragma unroll
  for (int jj = 0; jj < 9; ++jj) sb[jj * 256 + t] = cw[base + jj * 256 + t];
  __syncthreads();
  const int p = blk * 256 + t;
  #pragma unroll
  for (int q = 0; q < 9; ++q)
    Wp[(size_t)q * 2097152 + p] = f2bf(sb[t * 9 + q]);
}

// split-K combine: xc[b][o][s] = bf16(p0 + p1 + bias[o]); p is [kz][b*1024+s][o] f32
__global__ void addc_k(const float* __restrict__ p, const float* __restrict__ bias,
                       u16* __restrict__ xc) {
  __shared__ float tile[64][65];
  const int st = blockIdx.x;
  const int ot = blockIdx.y;
  const int b  = blockIdx.z;
  const int s0 = st * 64, o0 = ot * 64;
  const int t = threadIdx.x;
  const float* p1 = p + 8388608;
  #pragma unroll
  for (int jj = 0; jj < 16; ++jj) {
    int idx = jj * 256 + t;
    int si = idx >> 6, oi = idx & 63;
    const size_t m = ((size_t)b * 1024 + s0 + si) * 1024 + o0 + oi;
    tile[si][oi] = p[m] + p1[m] + bias[o0 + oi];
  }
  __syncthreads();
  #pragma unroll
  for (int jj = 0; jj < 16; ++jj) {
    int idx = jj * 256 + t;
    int oi = idx >> 6, si = idx & 63;
    xc[((size_t)b * 1024 + o0 + oi) * 1024 + s0 + si] = f2bf(tile[si][oi]);
  }
}

enum { GM_PLAIN = 0, GM_PROJ = 2 };

// ---------------- conv GEMM: halo reuse, 256x256 block, 4 waves, wave tile 128x128
// (proven r10/r12: 258 us, MfmaUtil 53.7%, conflicts 0)
__global__ __launch_bounds__(256, 1)
void conv9_k(const u16* __restrict__ Ap, const u16* __restrict__ B,
             float* __restrict__ Cf) {
  __shared__ u16 lds[2 * 12288 + 3 * 8192];
  const int tid = threadIdx.x;
  const int lane = tid & 63, w = tid >> 6;
  const int l15 = lane & 15, l4 = lane >> 4;

  const int bid = blockIdx.x;
  const int lb = (bid & 7) * 32 + (bid >> 3);
  const int kz = lb >> 7;
  const int tile = lb & 127;
  const int tm = tile >> 2, tn = tile & 3;
  const int row0 = tm * 256, col0 = tn * 256;
  const int b = tm >> 2;
  const int y0 = (tm & 3) * 8;
  const int hb = (b * 34 + y0) * 34;
  const int wr = (w >> 1) * 128, wc = (w & 1) * 128;
  const int chbase = kz * 1024;

  int pr[8];
  #pragma unroll
  for (int mi = 0; mi < 8; ++mi) {
    const int m = row0 + wr + mi * 16 + l15;
    const int y = (m >> 5) & 31, x = m & 31;
    pr[mi] = (y - y0 + 1) * 34 + x + 1;
  }

  const int srow = tid >> 2;
  const int sgc = tid & 3;

  f32x4 acc[8][8];
  #pragma unroll
  for (int i = 0; i < 8; ++i)
    #pragma unroll
    for (int jj = 0; jj < 8; ++jj)
      acc[i][jj] = (f32x4){0.f, 0.f, 0.f, 0.f};

  auto stageHalo = [&](int cc, int half) {
    u16* dst = lds + half * 12288;
    #pragma unroll
    for (int rnd = 0; rnd < 6; ++rnd) {
      const int row = rnd * 64 + srow;
      const int g = sgc ^ ((row >> 1) & 3);
      const u16* src = Ap + (size_t)(hb + row) * 2048 + chbase + cc * 32 + g * 8;
      gload16(src, dst + (size_t)(rnd * 256 + tid) * 8);
    }
  };
  auto stageB = [&](int cc, int q) {
    u16* dst = lds + 24576 + (q % 3) * 8192;
    #pragma unroll
    for (int rnd = 0; rnd < 4; ++rnd) {
      const int r = rnd * 64 + srow;
      const int g = sgc ^ ((r >> 1) & 3);
      const u16* src = B + ((size_t)q << 21) + (size_t)(col0 + r) * 2048
                       + chbase + cc * 32 + g * 8;
      gload16(src, dst + (size_t)(rnd * 256 + tid) * 8);
    }
  };

  constexpr int ddt[9] = {-35, -34, -33, -1, 0, 1, 33, 34, 35};
  constexpr int NC = 32;

  stageHalo(0, 0);
  stageHalo(1, 1);
  stageB(0, 0);
  stageB(0, 1);

  for (int cc = 0; cc < NC; ++cc) {
    const u16* hcur = lds + (cc & 1) * 12288;
    const bool interior = (cc >= 1 && cc <= NC - 2);
    #pragma unroll
    for (int q = 0; q < 9; ++q) {
      if ((q == 1 || q == 2) && interior) {
        asm volatile("s_waitcnt vmcnt(10)" ::: "memory");
      } else if (q == 8 && cc == NC - 1) {
        asm volatile("s_waitcnt vmcnt(0)" ::: "memory");
      } else {
        asm volatile("s_waitcnt vmcnt(4)" ::: "memory");
      }
      __builtin_amdgcn_s_barrier();
      {
        const int gp2 = cc * 9 + q + 2;
        if (gp2 <= NC * 9 - 1) {
          int qS = q + 2, ccS = cc;
          if (qS >= 9) { qS -= 9; ccS += 1; }
          stageB(ccS, qS);
        }
        if (q == 0 && cc >= 1 && cc <= NC - 2)
          stageHalo(cc + 1, (cc + 1) & 1);
      }
      {
        const u16* bq = lds + 24576 + (q % 3) * 8192;
        const int dd = ddt[q];
        short8 av[8], bv[8];
        #pragma unroll
        for (int mi = 0; mi < 8; ++mi) {
          const int hr = pr[mi] + dd;
          const int g = l4 ^ ((hr >> 1) & 3);
          av[mi] = *(const short8*)(hcur + hr * 32 + g * 8);
        }
        #pragma unroll
        for (int ni = 0; ni < 8; ++ni) {
          const int r = wc + ni * 16 + l15;
          const int g = l4 ^ ((r >> 1) & 3);
          bv[ni] = *(const short8*)(bq + r * 32 + g * 8);
        }
        __builtin_amdgcn_s_setprio(1);
        #pragma unroll
        for (int mi = 0; mi < 8; ++mi)
          #pragma unroll
          for (int ni = 0; ni < 8; ++ni)
            acc[mi][ni] = __builtin_amdgcn_mfma_f32_16x16x32_bf16(av[mi], bv[ni], acc[mi][ni], 0, 0, 0);
        __builtin_amdgcn_s_setprio(0);
      }
    }
  }

  #pragma unroll
  for (int mi = 0; mi < 8; ++mi) {
    #pragma unroll
    for (int ni = 0; ni < 8; ++ni) {
      #pragma unroll
      for (int j = 0; j < 4; ++j) {
        const int grow = row0 + wr + mi * 16 + l4 * 4 + j;
        const int gcol = col0 + wc + ni * 16 + l15;
        Cf[(size_t)kz * 8388608 + ((size_t)grow << 10) + gcol] = acc[mi][ni][j];
      }
    }
  }
}

// ---------------- GEMM A: 256x128 tile, BK=64 (proj only) ----------------
template<int MODE>
__global__ __launch_bounds__(512, 2)
void gemm3_k(const u16* __restrict__ A, const u16* __restrict__ B,
             u16* __restrict__ Cb, float* __restrict__ Cf,
             const float* __restrict__ bias, const float* __restrict__ resid,
             int Ktot, int ntn_sh) {
  __shared__ u16 lds[3 * 24576];
  const int tid = threadIdx.x;
  const int lane = tid & 63;
  const int w = tid >> 6;
  const int l15 = lane & 15, l4 = lane >> 4;

  const int nwg = gridDim.x;
  const int bid = blockIdx.x;
  const int lb = (bid & 7) * (nwg >> 3) + (bid >> 3);
  const int tm = lb >> ntn_sh;
  const int tn = lb & ((1 << ntn_sh) - 1);
  const int row0 = tm * 256, col0 = tn * 128;
  const int wr = (w >> 1) * 64, wc = (w & 1) * 64;

  const int sr = w * 8 + (lane >> 3);
  const int pp = (lane & 7) ^ (lane >> 3);

  f32x4 acc[4][4];
  #pragma unroll
  for (int i = 0; i < 4; ++i)
    #pragma unroll
    for (int jj = 0; jj < 4; ++jj)
      acc[i][jj] = (f32x4){0.f, 0.f, 0.f, 0.f};

  const int nK = Ktot >> 6;

  auto stage = [&](int kt, u16* buf) {
    u16* da = buf + (size_t)w * 512;
    u16* db = buf + 16384 + (size_t)w * 512;
    const int k0 = kt << 6;
    #pragma unroll
    for (int u = 0; u < 4; ++u) {
      const u16* ga = A + (size_t)(row0 + u * 64 + sr) * Ktot + k0 + pp * 8;
      gload16(ga, da + u * 4096);
    }
    #pragma unroll
    for (int u = 0; u < 2; ++u) {
      const u16* gb = B + (size_t)(col0 + u * 64 + sr) * Ktot + k0 + pp * 8;
      gload16(gb, db + u * 4096);
    }
  };

  auto compute = [&](const u16* buf) {
    const char* Ar = (const char*)buf;
    const char* Br = (const char*)(buf + 16384);
    #pragma unroll
    for (int ks = 0; ks < 2; ++ks) {
      const int bcol = ((ks << 6) + (l4 << 4)) ^ ((l15 & 7) << 4);
      short8 av[4], bv[4];
      #pragma unroll
      for (int mi = 0; mi < 4; ++mi)
        av[mi] = *(const short8*)(Ar + (wr + mi * 16 + l15) * 128 + bcol);
      #pragma unroll
      for (int ni = 0; ni < 4; ++ni)
        bv[ni] = *(const short8*)(Br + (wc + ni * 16 + l15) * 128 + bcol);
      __builtin_amdgcn_s_setprio(1);
      #pragma unroll
      for (int mi = 0; mi < 4; ++mi)
        #pragma unroll
        for (int ni = 0; ni < 4; ++ni)
          acc[mi][ni] = __builtin_amdgcn_mfma_f32_16x16x32_bf16(av[mi], bv[ni], acc[mi][ni], 0, 0, 0);
      __builtin_amdgcn_s_setprio(0);
    }
  };

  u16* pb0 = lds;
  u16* pb1 = lds + 24576;
  u16* pb2 = lds + 49152;

  stage(0, pb0);
  stage(1, pb1);
  for (int t = 0; t < nK; ++t) {
    if (t + 1 < nK) {
      asm volatile("s_waitcnt vmcnt(6)" ::: "memory");
    } else {
      asm volatile("s_waitcnt vmcnt(0)" ::: "memory");
    }
    __builtin_amdgcn_s_barrier();
    if (t + 2 < nK) stage(t + 2, pb2);
    compute(pb0);
    u16* tmp = pb0; pb0 = pb1; pb1 = pb2; pb2 = tmp;
  }

  #pragma unroll
  for (int mi = 0; mi < 4; ++mi) {
    #pragma unroll
    for (int ni = 0; ni < 4; ++ni) {
      #pragma unroll
      for (int j = 0; j < 4; ++j) {
        const int grow = row0 + wr + mi * 16 + l4 * 4 + j;
        const int gcol = col0 + wc + ni * 16 + l15;
        const float v = acc[mi][ni][j];
        if constexpr (MODE == GM_PLAIN) {
          Cb[((size_t)grow << 10) + gcol] = f2bf(v);
        } else if constexpr (MODE == GM_PROJ) {
          const size_t o = ((size_t)grow << 10) + gcol;
          Cf[o] = v + bias[gcol] + resid[o];
        }
      }
    }
  }
}

// ---------------- fused QKV GEMM: 768 blocks (sel 0=Q,1=K,2=V), BK=32, 8 waves ----------------
// V blocks write Vt via LDS transpose bounce (coalesced).
__global__ __launch_bounds__(512, 4)
void qkv_k(const u16* __restrict__ Ax1, const u16* __restrict__ Axc,
           const u16* __restrict__ Wq, const u16* __restrict__ Wk,
           const u16* __restrict__ Wv,
           u16* __restrict__ Qb, u16* __restrict__ Kb, u16* __restrict__ Vtb) {
  __shared__ u16 lds[3 * 12288];
  const int tid = threadIdx.x;
  const int lane = tid & 63;
  const int w = tid >> 6;
  const int l15 = lane & 15, l4 = lane >> 4;

  const int bid = blockIdx.x;             // grid = 768
  const int lb = (bid & 7) * 96 + (bid >> 3);
  const int sel = lb >> 8;                // 0=Q, 1=K, 2=V
  const int sub = lb & 255;
  const int tm = sub >> 3, tn = sub & 7;
  const int row0 = tm * 256, col0 = tn * 128;
  const int wr = (w >> 1) * 64, wc = (w & 1) * 64;

  const u16* A = (sel == 0) ? Ax1 : Axc;
  const u16* B = (sel == 0) ? Wq : (sel == 1) ? Wk : Wv;

  const int str = tid >> 2;
  const int sgc = tid & 3;

  f32x4 acc[4][4];
  #pragma unroll
  for (int i = 0; i < 4; ++i)
    #pragma unroll
    for (int jj = 0; jj < 4; ++jj)
      acc[i][jj] = (f32x4){0.f, 0.f, 0.f, 0.f};

  constexpr int Ktot = 1024;
  const int nKt = Ktot >> 5;

  auto stage = [&](int kt, u16* buf) {
    const int k0 = kt << 5;
    #pragma unroll
    for (int u = 0; u < 2; ++u) {
      const int r = u * 128 + str;
      const int swz = sgc ^ ((r >> 1) & 3);
      const u16* ga = A + (size_t)(row0 + r) * Ktot + k0 + swz * 8;
      gload16(ga, buf + ((size_t)u * 512 + tid) * 8);
    }
    {
      const int swz = sgc ^ ((str >> 1) & 3);
      const u16* gb = B + (size_t)(col0 + str) * Ktot + k0 + swz * 8;
      gload16(gb, buf + 8192 + (size_t)tid * 8);
    }
  };

  auto compute = [&](const u16* buf) {
    short8 av[4], bv[4];
    #pragma unroll
    for (int mi = 0; mi < 4; ++mi) {
      const int row = wr + mi * 16 + l15;
      const int g = l4 ^ ((row >> 1) & 3);
      av[mi] = *(const short8*)(buf + row * 32 + g * 8);
    }
    #pragma unroll
    for (int ni = 0; ni < 4; ++ni) {
      const int row = wc + ni * 16 + l15;
      const int g = l4 ^ ((row >> 1) & 3);
      bv[ni] = *(const short8*)(buf + 8192 + row * 32 + g * 8);
    }
    __builtin_amdgcn_s_setprio(1);
    #pragma unroll
    for (int mi = 0; mi < 4; ++mi)
      #pragma unroll
      for (int ni = 0; ni < 4; ++ni)
        acc[mi][ni] = __builtin_amdgcn_mfma_f32_16x16x32_bf16(av[mi], bv[ni], acc[mi][ni], 0, 0, 0);
    __builtin_amdgcn_s_setprio(0);
  };

  u16* pb0 = lds;
  u16* pb1 = lds + 12288;
  u16* pb2 = lds + 24576;

  stage(0, pb0);
  stage(1, pb1);
  for (int t = 0; t < nKt; ++t) {
    if (t + 1 < nKt) {
      asm volatile("s_waitcnt vmcnt(3)" ::: "memory");
    } else {
      asm volatile("s_waitcnt vmcnt(0)" ::: "memory");
    }
    __builtin_amdgcn_s_barrier();
    if (t + 2 < nKt) stage(t + 2, pb2);
    compute(pb0);
    u16* tmp = pb0; pb0 = pb1; pb1 = pb2; pb2 = tmp;
  }

  if (sel < 2) {
    u16* Cb = (sel == 0) ? Qb : Kb;
    #pragma unroll
    for (int mi = 0; mi < 4; ++mi)
      #pragma unroll
      for (int ni = 0; ni < 4; ++ni)
        #pragma unroll
        for (int j = 0; j < 4; ++j) {
          const int grow = row0 + wr + mi * 16 + l4 * 4 + j;
          const int gcol = col0 + wc + ni * 16 + l15;
          Cb[((size_t)grow << 10) + gcol] = f2bf(acc[mi][ni][j]);
        }
  } else {
    // V block: transpose 256x128 via LDS (padded rows), write Vt coalesced.
    const int h = tn;
    const int bb = row0 >> 10;
    u16* tb = lds;
    #pragma unroll
    for (int chunk = 0; chunk < 4; ++chunk) {
      __syncthreads();
      if ((w >> 1) == chunk) {
        #pragma unroll
        for (int mi = 0; mi < 4; ++mi)
          #pragma unroll
          for (int ni = 0; ni < 4; ++ni)
            #pragma unroll
            for (int j = 0; j < 4; ++j) {
              const int d = wc + ni * 16 + l15;
              const int t = mi * 16 + l4 * 4 + j;
              tb[d * 66 + t] = f2bf(acc[mi][ni][j]);
            }
      }
      __syncthreads();
      {
        const int r = tid >> 2;
        const int c0 = (tid & 3) * 16;
        const int tok = (row0 & 1023) + chunk * 64 + c0;
        uint4 v0 = *(const uint4*)(tb + r * 66 + c0);
        uint4 v1 = *(const uint4*)(tb + r * 66 + c0 + 8);
        u16* dst = Vtb + (((size_t)((bb * 8 + h) * 128 + r)) << 10) + tok;
        *(uint4*)dst = v0;
        *(uint4*)(dst + 8) = v1;
      }
    }
  }
}

// ---------------- flash attention (double-buffered, KV-locality XCD remap) ----------------
__global__ __launch_bounds__(256, 2)
void attn2_k(const u16* __restrict__ Q, const u16* __restrict__ K,
             const u16* __restrict__ Vt, u16* __restrict__ O) {
  __shared__ u16 Ks[2][64 * 128];
  __shared__ u16 Vs[2][128 * 64];
  __shared__ u16 Plds[4][16 * 72];
  const int bid = blockIdx.x;                 // grid = 1024
  const int lb = (bid & 7) * 128 + (bid >> 3);
  const int bh = lb >> 4;
  const int mtile = lb & 15;
  const int b = bh >> 3, h = bh & 7;
  const int tid = threadIdx.x, lane = tid & 63, w = tid >> 6;
  const int l15 = lane & 15, l4 = lane >> 4;

  short8 qf[4];
  {
    const int qrow = b * 1024 + mtile * 64 + w * 16 + l15;
    const u16* qb = Q + ((size_t)qrow << 10) + h * 128;
    #pragma unroll
    for (int kk = 0; kk < 4; ++kk)
      qf[kk] = *(const short8*)(qb + kk * 32 + l4 * 8);
  }

  f32x4 o[8];
  #pragma unroll
  for (int db = 0; db < 8; ++db) o[db] = (f32x4){0.f, 0.f, 0.f, 0.f};
  float mrow[4], lrow[4];
  #pragma unroll
  for (int j = 0; j < 4; ++j) { mrow[j] = -1e30f; lrow[j] = 0.f; }
  const float scale = 0.08838834764831845f;

  auto stageKV = [&](int kt, int half) {
    #pragma unroll
    for (int j = 0; j < 4; ++j) {
      const int c = (j * 4 + w) * 64 + lane;
      const int r = c >> 4;
      const int coff = (((c & 15) ^ (r & 7)) << 3);
      const u16* gp = K + ((size_t)(b * 1024 + kt * 64 + r) << 10) + h * 128 + coff;
      gload16(gp, (void*)(Ks[half] + (j * 4 + w) * 512));
    }
    #pragma unroll
    for (int j = 0; j < 4; ++j) {
      const int c = (j * 4 + w) * 64 + lane;
      const int r = c >> 3;
      const int coff = (((c & 7) ^ (r & 7)) << 3);
      const u16* gp = Vt + ((size_t)((b * 8 + h) * 128 + r) << 10) + kt * 64 + coff;
      gload16(gp, (void*)(Vs[half] + (j * 4 + w) * 512));
    }
  };

  stageKV(0, 0);
  for (int kt = 0; kt < 16; ++kt) {
    const int cur = kt & 1;
    asm volatile("s_waitcnt vmcnt(0)" ::: "memory");
    __builtin_amdgcn_s_barrier();
    if (kt + 1 < 16) stageKV(kt + 1, cur ^ 1);

    const u16* ks_ = Ks[cur];
    const u16* vs_ = Vs[cur];
    f32x4 s[4];
    #pragma unroll
    for (int cb = 0; cb < 4; ++cb) {
      s[cb] = (f32x4){0.f, 0.f, 0.f, 0.f};
      #pragma unroll
      for (int kk = 0; kk < 4; ++kk) {
        const int col = (kk * 32 + l4 * 8) ^ ((l15 & 7) << 3);
        short8 bK = *(const short8*)(ks_ + (cb * 16 + l15) * 128 + col);
        __builtin_amdgcn_s_setprio(1);
        s[cb] = __builtin_amdgcn_mfma_f32_16x16x32_bf16(qf[kk], bK, s[cb], 0, 0, 0);
        __builtin_amdgcn_s_setprio(0);
      }
    }
    #pragma unroll
    for (int cb = 0; cb < 4; ++cb) {
      s[cb][0] *= scale; s[cb][1] *= scale; s[cb][2] *= scale; s[cb][3] *= scale;
    }
    #pragma unroll
    for (int j = 0; j < 4; ++j) {
      float mx = fmaxf(fmaxf(s[0][j], s[1][j]), fmaxf(s[2][j], s[3][j]));
      #pragma unroll
      for (int off = 8; off >= 1; off >>= 1)
        mx = fmaxf(mx, __shfl_xor(mx, off, 64));
      const float mn = fmaxf(mrow[j], mx);
      const float fac = __expf(mrow[j] - mn);
      mrow[j] = mn;
      float rs = 0.f;
      #pragma unroll
      for (int cb = 0; cb < 4; ++cb) {
        const float p = __expf(s[cb][j] - mn);
        s[cb][j] = p;
        rs += p;
      }
      #pragma unroll
      for (int off = 8; off >= 1; off >>= 1)
        rs += __shfl_xor(rs, off, 64);
      lrow[j] = lrow[j] * fac + rs;
      #pragma unroll
      for (int db = 0; db < 8; ++db) o[db][j] *= fac;
    }
    u16* pl = Plds[w];
    #pragma unroll
    for (int cb = 0; cb < 4; ++cb)
      #pragma unroll
      for (int j = 0; j < 4; ++j)
        pl[(l4 * 4 + j) * 72 + cb * 16 + l15] = f2bf(s[cb][j]);
    asm volatile("s_waitcnt lgkmcnt(0)" ::: "memory");
    __builtin_amdgcn_sched_barrier(0);
    short8 ap[2];
    #pragma unroll
    for (int ks2 = 0; ks2 < 2; ++ks2)
      ap[ks2] = *(const short8*)(pl + l15 * 72 + ks2 * 32 + l4 * 8);
    #pragma unroll
    for (int db = 0; db < 8; ++db) {
      #pragma unroll
      for (int ks2 = 0; ks2 < 2; ++ks2) {
        const int col = (ks2 * 32 + l4 * 8) ^ ((l15 & 7) << 3);
        short8 bV = *(const short8*)(vs_ + (db * 16 + l15) * 64 + col);
        __builtin_amdgcn_s_setprio(1);
        o[db] = __builtin_amdgcn_mfma_f32_16x16x32_bf16(ap[ks2], bV, o[db], 0, 0, 0);
        __builtin_amdgcn_s_setprio(0);
      }
    }
  }
  #pragma unroll
  for (int db = 0; db < 8; ++db) {
    #pragma unroll
    for (int j = 0; j < 4; ++j) {
      const int grow = b * 1024 + mtile * 64 + w * 16 + l4 * 4 + j;
      const int gcol = h * 128 + db * 16 + l15;
      O[((size_t)grow << 10) + gcol] = f2bf(o[db][j] / lrow[j]);
    }
  }
}

// ---------------- launch ----------------

extern "C" void kernel_launch(void* const* d_in, const int* in_sizes, int n_in,
                              void* d_out, int out_size, void* d_ws, size_t ws_size,
                              hipStream_t stream) {
  const float* x1     = (const float*)d_in[0];
  const float* x2     = (const float*)d_in[1];
  const float* conv_w = (const float*)d_in[2];
  const float* conv_b = (const float*)d_in[3];
  const float* wq     = (const float*)d_in[4];
  const float* wk     = (const float*)d_in[5];
  const float* wv     = (const float*)d_in[6];
  const float* proj_w = (const float*)d_in[7];
  const float* proj_b = (const float*)d_in[8];
  float* out = (float*)d_out;

  char* ws = (char*)d_ws;
  size_t off = 0;
  auto alloc = [&](size_t bytes) -> void* {
    void* p = ws + off;
    off += (bytes + 255) & ~(size_t)255;
    return p;
  };
  u16* x1b  = (u16*)alloc(8192ULL * 1024 * 2);
  u16* in_t_pad = (u16*)alloc((9248ULL + 96) * 2048 * 2);
  const size_t pad_bytes = 9248ULL * 2048 * 2;
  u16* Wp   = (u16*)alloc(9ULL * 2097152 * 2);
  u16* wqb  = (u16*)alloc(1048576ULL * 2);
  u16* wkb  = (u16*)alloc(1048576ULL * 2);
  u16* wvb  = (u16*)alloc(1048576ULL * 2);
  u16* pjb  = (u16*)alloc(1048576ULL * 2);
  u16* xc   = (u16*)alloc(8192ULL * 1024 * 2);
  u16* Qb   = (u16*)alloc(8192ULL * 1024 * 2);
  u16* Kb   = (u16*)alloc(8192ULL * 1024 * 2);
  u16* Vtb  = (u16*)alloc(8192ULL * 1024 * 2);
  u16* Ob   = (u16*)alloc(8192ULL * 1024 * 2);
  float* pConv = (float*)Qb;   // split-K f32 partials alias Qb..Ob

  // prep
  (void)hipMemsetAsync(in_t_pad, 0, pad_bytes + 96ULL * 2048 * 2, stream);
  cast4_k<<<dim3(1024, 4), 256, 0, stream>>>(wq, wk, wv, proj_w, wqb, wkb, wvb, pjb);
  build_pad<<<dim3(32, 16, 8), 256, 0, stream>>>(x1, x2, in_t_pad, x1b);
  pack_wp<<<8192, 256, 0, stream>>>(conv_w, Wp);

  // conv: halo-reuse implicit GEMM (proven r10/r12 config), split-K x2
  conv9_k<<<256, 256, 0, stream>>>(in_t_pad, Wp, pConv);
  addc_k<<<dim3(16, 16, 8), 256, 0, stream>>>(pConv, conv_b, xc);
  // fused Q + K + V (768 blocks; V transposed via LDS bounce)
  qkv_k<<<768, 512, 0, stream>>>(x1b, xc, wqb, wkb, wvb, Qb, Kb, Vtb);
  // attention (1D grid, KV-locality remap)
  attn2_k<<<1024, 256, 0, stream>>>(Qb, Kb, Vtb, Ob);
  // projection + bias + residual
  gemm3_k<GM_PROJ><<<256, 512, 0, stream>>>(Ob, pjb, nullptr, out, proj_b, x1, 1024, 3);
}

// Round 15
// 492.669 us; speedup vs baseline: 1.1200x; 1.0097x over previous
//
#include <hip/hip_runtime.h>
#include <hip/hip_bf16.h>
#include <cstdint>
#include <cstddef>

typedef __attribute__((ext_vector_type(8))) short short8;
typedef __attribute__((ext_vector_type(4))) float f32x4;
typedef unsigned short u16;

static __device__ __forceinline__ u16 f2bf(float f) {
  __hip_bfloat16 h = __float2bfloat16(f);
  return *reinterpret_cast<u16*>(&h);
}

static __device__ __forceinline__ void gload16(const void* g, void* l) {
  __builtin_amdgcn_global_load_lds(
      (const __attribute__((address_space(1))) void*)g,
      (__attribute__((address_space(3))) void*)l, 16, 0, 0);
}

// ---------------- prep kernels ----------------

// zero only the border pad positions of in_t_pad (4.3 MB instead of 38 MB memset)
__global__ void border0_k(u16* __restrict__ in_t_pad) {
  const int i = blockIdx.x;   // 0..131
  const int b = blockIdx.y;   // 0..7
  int py, px;
  if (i < 34)      { py = 0;             px = i; }
  else if (i < 68) { py = 33;            px = i - 34; }
  else             { int j = i - 68;     py = 1 + (j >> 1); px = (j & 1) * 33; }
  u16* dst = in_t_pad + ((size_t)((b * 34 + py) * 34 + px)) * 2048 + threadIdx.x * 8;
  *(uint4*)dst = (uint4){0u, 0u, 0u, 0u};
}

__global__ void cast4_k(const float* __restrict__ a, const float* __restrict__ b,
                        const float* __restrict__ c, const float* __restrict__ d,
                        u16* __restrict__ oa, u16* __restrict__ ob,
                        u16* __restrict__ oc, u16* __restrict__ od) {
  const int which = blockIdx.y;
  const float* src = (which == 0) ? a : (which == 1) ? b : (which == 2) ? c : d;
  u16* dst = (which == 0) ? oa : (which == 1) ? ob : (which == 2) ? oc : od;
  int i = blockIdx.x * 256 + threadIdx.x;
  float4 v = ((const float4*)src)[i];
  union { u16 u[4]; uint2 p; } r;
  r.u[0] = f2bf(v.x); r.u[1] = f2bf(v.y); r.u[2] = f2bf(v.z); r.u[3] = f2bf(v.w);
  ((uint2*)dst)[i] = r.p;
}

// in_t_pad[(b*34 + y+1)*34 + x+1][i] = bf16( concat(x1,x2)[b][i][y*32+x] )
__global__ void build_pad(const float* __restrict__ x1, const float* __restrict__ x2,
                          u16* __restrict__ in_t_pad, u16* __restrict__ x1b) {
  __shared__ float tile[64][65];
  const int it = blockIdx.x;
  const int st = blockIdx.y;
  const int b  = blockIdx.z;
  const int i0 = it * 64, s0 = st * 64;
  const bool isx1 = (i0 < 1024);
  const float* src = isx1
      ? x1 + ((size_t)b * 1024 + i0) * 1024
      : x2 + ((size_t)b * 1024 + (i0 - 1024)) * 1024;
  const int t = threadIdx.x;
  #pragma unroll
  for (int jj = 0; jj < 16; ++jj) {
    int idx = jj * 256 + t;
    int ii = idx >> 6, si = idx & 63;
    float v = src[(size_t)ii * 1024 + s0 + si];
    tile[ii][si] = v;
    if (isx1)
      x1b[((size_t)b * 1024 + i0 + ii) * 1024 + s0 + si] = f2bf(v);
  }
  __syncthreads();
  #pragma unroll
  for (int jj = 0; jj < 16; ++jj) {
    int idx = jj * 256 + t;
    int si = idx >> 6, ii = idx & 63;
    const int s = s0 + si;
    const int prow = (b * 34 + (s >> 5) + 1) * 34 + (s & 31) + 1;
    in_t_pad[(size_t)prow * 2048 + i0 + ii] = f2bf(tile[ii][si]);
  }
}

// Wp[q][o][i] = bf16( conv_w[o][i][q] ),  q = ky*3+kx
__global__ void pack_wp(const float* __restrict__ cw, u16* __restrict__ Wp) {
  __shared__ float sb[2304];
  const int blk = blockIdx.x;
  const int t = threadIdx.x;
  const size_t base = (size_t)blk * 2304;
  #pragma unroll
  for (int jj = 0; jj < 9; ++jj) sb[jj * 256 + t] = cw[base + jj * 256 + t];
  __syncthreads();
  const int p = blk * 256 + t;
  #pragma unroll
  for (int q = 0; q < 9; ++q)
    Wp[(size_t)q * 2097152 + p] = f2bf(sb[t * 9 + q]);
}

// split-K combine: xc[b][o][s] = bf16(p0 + p1 + bias[o]); p is [kz][b*1024+s][o] f32
__global__ void addc_k(const float* __restrict__ p, const float* __restrict__ bias,
                       u16* __restrict__ xc) {
  __shared__ float tile[64][65];
  const int st = blockIdx.x;
  const int ot = blockIdx.y;
  const int b  = blockIdx.z;
  const int s0 = st * 64, o0 = ot * 64;
  const int t = threadIdx.x;
  const float* p1 = p + 8388608;
  #pragma unroll
  for (int jj = 0; jj < 16; ++jj) {
    int idx = jj * 256 + t;
    int si = idx >> 6, oi = idx & 63;
    const size_t m = ((size_t)b * 1024 + s0 + si) * 1024 + o0 + oi;
    tile[si][oi] = p[m] + p1[m] + bias[o0 + oi];
  }
  __syncthreads();
  #pragma unroll
  for (int jj = 0; jj < 16; ++jj) {
    int idx = jj * 256 + t;
    int oi = idx >> 6, si = idx & 63;
    xc[((size_t)b * 1024 + o0 + oi) * 1024 + s0 + si] = f2bf(tile[si][oi]);
  }
}

enum { GM_PLAIN = 0, GM_PROJ = 2 };

// ---------------- conv GEMM: halo reuse, 256x256 block, 4 waves, wave tile 128x128
// (proven r10/r12/r14: 257.5 us, MfmaUtil 53.7%, conflicts 0) -- FROZEN
__global__ __launch_bounds__(256, 1)
void conv9_k(const u16* __restrict__ Ap, const u16* __restrict__ B,
             float* __restrict__ Cf) {
  __shared__ u16 lds[2 * 12288 + 3 * 8192];
  const int tid = threadIdx.x;
  const int lane = tid & 63, w = tid >> 6;
  const int l15 = lane & 15, l4 = lane >> 4;

  const int bid = blockIdx.x;
  const int lb = (bid & 7) * 32 + (bid >> 3);
  const int kz = lb >> 7;
  const int tile = lb & 127;
  const int tm = tile >> 2, tn = tile & 3;
  const int row0 = tm * 256, col0 = tn * 256;
  const int b = tm >> 2;
  const int y0 = (tm & 3) * 8;
  const int hb = (b * 34 + y0) * 34;
  const int wr = (w >> 1) * 128, wc = (w & 1) * 128;
  const int chbase = kz * 1024;

  int pr[8];
  #pragma unroll
  for (int mi = 0; mi < 8; ++mi) {
    const int m = row0 + wr + mi * 16 + l15;
    const int y = (m >> 5) & 31, x = m & 31;
    pr[mi] = (y - y0 + 1) * 34 + x + 1;
  }

  const int srow = tid >> 2;
  const int sgc = tid & 3;

  f32x4 acc[8][8];
  #pragma unroll
  for (int i = 0; i < 8; ++i)
    #pragma unroll
    for (int jj = 0; jj < 8; ++jj)
      acc[i][jj] = (f32x4){0.f, 0.f, 0.f, 0.f};

  auto stageHalo = [&](int cc, int half) {
    u16* dst = lds + half * 12288;
    #pragma unroll
    for (int rnd = 0; rnd < 6; ++rnd) {
      const int row = rnd * 64 + srow;
      const int g = sgc ^ ((row >> 1) & 3);
      const u16* src = Ap + (size_t)(hb + row) * 2048 + chbase + cc * 32 + g * 8;
      gload16(src, dst + (size_t)(rnd * 256 + tid) * 8);
    }
  };
  auto stageB = [&](int cc, int q) {
    u16* dst = lds + 24576 + (q % 3) * 8192;
    #pragma unroll
    for (int rnd = 0; rnd < 4; ++rnd) {
      const int r = rnd * 64 + srow;
      const int g = sgc ^ ((r >> 1) & 3);
      const u16* src = B + ((size_t)q << 21) + (size_t)(col0 + r) * 2048
                       + chbase + cc * 32 + g * 8;
      gload16(src, dst + (size_t)(rnd * 256 + tid) * 8);
    }
  };

  constexpr int ddt[9] = {-35, -34, -33, -1, 0, 1, 33, 34, 35};
  constexpr int NC = 32;

  stageHalo(0, 0);
  stageHalo(1, 1);
  stageB(0, 0);
  stageB(0, 1);

  for (int cc = 0; cc < NC; ++cc) {
    const u16* hcur = lds + (cc & 1) * 12288;
    const bool interior = (cc >= 1 && cc <= NC - 2);
    #pragma unroll
    for (int q = 0; q < 9; ++q) {
      if ((q == 1 || q == 2) && interior) {
        asm volatile("s_waitcnt vmcnt(10)" ::: "memory");
      } else if (q == 8 && cc == NC - 1) {
        asm volatile("s_waitcnt vmcnt(0)" ::: "memory");
      } else {
        asm volatile("s_waitcnt vmcnt(4)" ::: "memory");
      }
      __builtin_amdgcn_s_barrier();
      {
        const int gp2 = cc * 9 + q + 2;
        if (gp2 <= NC * 9 - 1) {
          int qS = q + 2, ccS = cc;
          if (qS >= 9) { qS -= 9; ccS += 1; }
          stageB(ccS, qS);
        }
        if (q == 0 && cc >= 1 && cc <= NC - 2)
          stageHalo(cc + 1, (cc + 1) & 1);
      }
      {
        const u16* bq = lds + 24576 + (q % 3) * 8192;
        const int dd = ddt[q];
        short8 av[8], bv[8];
        #pragma unroll
        for (int mi = 0; mi < 8; ++mi) {
          const int hr = pr[mi] + dd;
          const int g = l4 ^ ((hr >> 1) & 3);
          av[mi] = *(const short8*)(hcur + hr * 32 + g * 8);
        }
        #pragma unroll
        for (int ni = 0; ni < 8; ++ni) {
          const int r = wc + ni * 16 + l15;
          const int g = l4 ^ ((r >> 1) & 3);
          bv[ni] = *(const short8*)(bq + r * 32 + g * 8);
        }
        __builtin_amdgcn_s_setprio(1);
        #pragma unroll
        for (int mi = 0; mi < 8; ++mi)
          #pragma unroll
          for (int ni = 0; ni < 8; ++ni)
            acc[mi][ni] = __builtin_amdgcn_mfma_f32_16x16x32_bf16(av[mi], bv[ni], acc[mi][ni], 0, 0, 0);
        __builtin_amdgcn_s_setprio(0);
      }
    }
  }

  #pragma unroll
  for (int mi = 0; mi < 8; ++mi) {
    #pragma unroll
    for (int ni = 0; ni < 8; ++ni) {
      #pragma unroll
      for (int j = 0; j < 4; ++j) {
        const int grow = row0 + wr + mi * 16 + l4 * 4 + j;
        const int gcol = col0 + wc + ni * 16 + l15;
        Cf[(size_t)kz * 8388608 + ((size_t)grow << 10) + gcol] = acc[mi][ni][j];
      }
    }
  }
}

// ---------------- fused QKV GEMM, conv9 geometry (256x256 tile, 4 waves, 128x128
// wave tile, BK=32, triple-buffered 96KB, 1 blk/CU). grid 384 = Q(128) + K(128)
// + V(128 w/ LDS-transpose epilogue). vmcnt ledger: stage=8 loads -> vmcnt(8).
__global__ __launch_bounds__(256, 1)
void qkv2_k(const u16* __restrict__ x1b, const u16* __restrict__ xc,
            const u16* __restrict__ wqb, const u16* __restrict__ wkb,
            const u16* __restrict__ wvb,
            u16* __restrict__ Qb, u16* __restrict__ Kb, u16* __restrict__ Vtb) {
  __shared__ u16 lds[3 * 16384];   // per buf: A 256x32 (8192 u16) + B 256x32
  const int tid = threadIdx.x;
  const int lane = tid & 63, w = tid >> 6;
  const int l15 = lane & 15, l4 = lane >> 4;

  const int bid = blockIdx.x;             // grid = 384 (384%8==0, bijective)
  const int lb = (bid & 7) * 48 + (bid >> 3);
  int sel, tm, tn;
  const u16 *A, *B;
  if (lb < 128) {
    sel = 0; tm = lb >> 2; tn = lb & 3;
    A = x1b; B = wqb + (size_t)tn * 256 * 1024;
  } else {
    const int kv = lb - 128;
    tm = kv >> 3; tn = kv & 7;
    A = xc;
    if (tn < 4) { sel = 1; B = wkb + (size_t)tn * 256 * 1024; }
    else        { sel = 2; B = wvb + (size_t)(tn - 4) * 256 * 1024; }
  }
  const int row0 = tm * 256;
  const int wr = (w >> 1) * 128, wc = (w & 1) * 128;

  const int srow = tid >> 2;   // 0..63
  const int sgc = tid & 3;

  f32x4 acc[8][8];
  #pragma unroll
  for (int i = 0; i < 8; ++i)
    #pragma unroll
    for (int jj = 0; jj < 8; ++jj)
      acc[i][jj] = (f32x4){0.f, 0.f, 0.f, 0.f};

  auto stage = [&](int kt, u16* buf) {
    const int k0 = kt << 5;
    #pragma unroll
    for (int u = 0; u < 4; ++u) {
      const int r = u * 64 + srow;
      const int g = sgc ^ ((r >> 1) & 3);
      gload16(A + (size_t)(row0 + r) * 1024 + k0 + g * 8,
              buf + (size_t)(u * 256 + tid) * 8);
    }
    #pragma unroll
    for (int u = 0; u < 4; ++u) {
      const int r = u * 64 + srow;
      const int g = sgc ^ ((r >> 1) & 3);
      gload16(B + (size_t)r * 1024 + k0 + g * 8,
              buf + 8192 + (size_t)(u * 256 + tid) * 8);
    }
  };

  auto compute = [&](const u16* buf) {
    short8 av[8], bv[8];
    #pragma unroll
    for (int mi = 0; mi < 8; ++mi) {
      const int r = wr + mi * 16 + l15;
      const int g = l4 ^ ((r >> 1) & 3);
      av[mi] = *(const short8*)(buf + r * 32 + g * 8);
    }
    #pragma unroll
    for (int ni = 0; ni < 8; ++ni) {
      const int r = wc + ni * 16 + l15;
      const int g = l4 ^ ((r >> 1) & 3);
      bv[ni] = *(const short8*)(buf + 8192 + r * 32 + g * 8);
    }
    __builtin_amdgcn_s_setprio(1);
    #pragma unroll
    for (int mi = 0; mi < 8; ++mi)
      #pragma unroll
      for (int ni = 0; ni < 8; ++ni)
        acc[mi][ni] = __builtin_amdgcn_mfma_f32_16x16x32_bf16(av[mi], bv[ni], acc[mi][ni], 0, 0, 0);
    __builtin_amdgcn_s_setprio(0);
  };

  u16* pb0 = lds;
  u16* pb1 = lds + 16384;
  u16* pb2 = lds + 32768;

  stage(0, pb0);
  stage(1, pb1);
  for (int t = 0; t < 32; ++t) {
    if (t + 1 < 32) {
      asm volatile("s_waitcnt vmcnt(8)" ::: "memory");
    } else {
      asm volatile("s_waitcnt vmcnt(0)" ::: "memory");
    }
    __builtin_amdgcn_s_barrier();
    if (t + 2 < 32) stage(t + 2, pb2);
    compute(pb0);
    u16* tmp = pb0; pb0 = pb1; pb1 = pb2; pb2 = tmp;
  }

  if (sel < 2) {
    // Q / K: direct write, gcol = tn*256 + wc + ni*16 + l15
    u16* out = (sel == 0) ? Qb : Kb;
    const int colbase = tn * 256;
    #pragma unroll
    for (int mi = 0; mi < 8; ++mi)
      #pragma unroll
      for (int ni = 0; ni < 8; ++ni)
        #pragma unroll
        for (int j = 0; j < 4; ++j) {
          const int grow = row0 + wr + mi * 16 + l4 * 4 + j;
          const int gcol = colbase + wc + ni * 16 + l15;
          out[((size_t)grow << 10) + gcol] = f2bf(acc[mi][ni][j]);
        }
  } else {
    // V: transpose 256(tok) x 256(d) via LDS bounce -> Vt[(b*8+h)*128+d][tok]
    const int d0 = (tn - 4) * 256;
    const int bb = row0 >> 10;
    const int tok0 = row0 & 1023;
    u16* tb = lds;   // [256][66] u16 = 33.8 KB (staging loop done)
    #pragma unroll
    for (int c = 0; c < 4; ++c) {
      __syncthreads();
      if ((w >> 1) == (c >> 1)) {
        const int mib = (c & 1) * 4;
        #pragma unroll
        for (int m2 = 0; m2 < 4; ++m2) {
          const int mi = mib + m2;
          #pragma unroll
          for (int ni = 0; ni < 8; ++ni) {
            const int d = wc + ni * 16 + l15;
            #pragma unroll
            for (int j = 0; j < 4; ++j) {
              const int tl = mi * 16 + l4 * 4 + j - (c & 1) * 64;  // 0..63
              tb[d * 66 + tl] = f2bf(acc[mi][ni][j]);
            }
          }
        }
      }
      __syncthreads();
      #pragma unroll
      for (int p = 0; p < 4; ++p) {
        const int dr = p * 64 + (tid >> 2);
        const int t0 = (tid & 3) * 16;
        uint4 v0 = *(const uint4*)(tb + dr * 66 + t0);
        uint4 v1 = *(const uint4*)(tb + dr * 66 + t0 + 8);
        const int dg = d0 + dr;
        u16* dst = Vtb + (((size_t)((bb * 8 + (dg >> 7)) * 128 + (dg & 127))) << 10)
                   + tok0 + c * 64 + t0;
        *(uint4*)dst = v0;
        *(uint4*)(dst + 8) = v1;
      }
    }
  }
}

// ---------------- GEMM A: 256x128 tile, BK=64 (proj only) ----------------
template<int MODE>
__global__ __launch_bounds__(512, 2)
void gemm3_k(const u16* __restrict__ A, const u16* __restrict__ B,
             u16* __restrict__ Cb, float* __restrict__ Cf,
             const float* __restrict__ bias, const float* __restrict__ resid,
             int Ktot, int ntn_sh) {
  __shared__ u16 lds[3 * 24576];
  const int tid = threadIdx.x;
  const int lane = tid & 63;
  const int w = tid >> 6;
  const int l15 = lane & 15, l4 = lane >> 4;

  const int nwg = gridDim.x;
  const int bid = blockIdx.x;
  const int lb = (bid & 7) * (nwg >> 3) + (bid >> 3);
  const int tm = lb >> ntn_sh;
  const int tn = lb & ((1 << ntn_sh) - 1);
  const int row0 = tm * 256, col0 = tn * 128;
  const int wr = (w >> 1) * 64, wc = (w & 1) * 64;

  const int sr = w * 8 + (lane >> 3);
  const int pp = (lane & 7) ^ (lane >> 3);

  f32x4 acc[4][4];
  #pragma unroll
  for (int i = 0; i < 4; ++i)
    #pragma unroll
    for (int jj = 0; jj < 4; ++jj)
      acc[i][jj] = (f32x4){0.f, 0.f, 0.f, 0.f};

  const int nK = Ktot >> 6;

  auto stage = [&](int kt, u16* buf) {
    u16* da = buf + (size_t)w * 512;
    u16* db = buf + 16384 + (size_t)w * 512;
    const int k0 = kt << 6;
    #pragma unroll
    for (int u = 0; u < 4; ++u) {
      const u16* ga = A + (size_t)(row0 + u * 64 + sr) * Ktot + k0 + pp * 8;
      gload16(ga, da + u * 4096);
    }
    #pragma unroll
    for (int u = 0; u < 2; ++u) {
      const u16* gb = B + (size_t)(col0 + u * 64 + sr) * Ktot + k0 + pp * 8;
      gload16(gb, db + u * 4096);
    }
  };

  auto compute = [&](const u16* buf) {
    const char* Ar = (const char*)buf;
    const char* Br = (const char*)(buf + 16384);
    #pragma unroll
    for (int ks = 0; ks < 2; ++ks) {
      const int bcol = ((ks << 6) + (l4 << 4)) ^ ((l15 & 7) << 4);
      short8 av[4], bv[4];
      #pragma unroll
      for (int mi = 0; mi < 4; ++mi)
        av[mi] = *(const short8*)(Ar + (wr + mi * 16 + l15) * 128 + bcol);
      #pragma unroll
      for (int ni = 0; ni < 4; ++ni)
        bv[ni] = *(const short8*)(Br + (wc + ni * 16 + l15) * 128 + bcol);
      __builtin_amdgcn_s_setprio(1);
      #pragma unroll
      for (int mi = 0; mi < 4; ++mi)
        #pragma unroll
        for (int ni = 0; ni < 4; ++ni)
          acc[mi][ni] = __builtin_amdgcn_mfma_f32_16x16x32_bf16(av[mi], bv[ni], acc[mi][ni], 0, 0, 0);
      __builtin_amdgcn_s_setprio(0);
    }
  };

  u16* pb0 = lds;
  u16* pb1 = lds + 24576;
  u16* pb2 = lds + 49152;

  stage(0, pb0);
  stage(1, pb1);
  for (int t = 0; t < nK; ++t) {
    if (t + 1 < nK) {
      asm volatile("s_waitcnt vmcnt(6)" ::: "memory");
    } else {
      asm volatile("s_waitcnt vmcnt(0)" ::: "memory");
    }
    __builtin_amdgcn_s_barrier();
    if (t + 2 < nK) stage(t + 2, pb2);
    compute(pb0);
    u16* tmp = pb0; pb0 = pb1; pb1 = pb2; pb2 = tmp;
  }

  #pragma unroll
  for (int mi = 0; mi < 4; ++mi) {
    #pragma unroll
    for (int ni = 0; ni < 4; ++ni) {
      #pragma unroll
      for (int j = 0; j < 4; ++j) {
        const int grow = row0 + wr + mi * 16 + l4 * 4 + j;
        const int gcol = col0 + wc + ni * 16 + l15;
        const float v = acc[mi][ni][j];
        if constexpr (MODE == GM_PLAIN) {
          Cb[((size_t)grow << 10) + gcol] = f2bf(v);
        } else if constexpr (MODE == GM_PROJ) {
          const size_t o = ((size_t)grow << 10) + gcol;
          Cf[o] = v + bias[gcol] + resid[o];
        }
      }
    }
  }
}

// ---------------- flash attention (double-buffered, KV-locality XCD remap) ----------------
__global__ __launch_bounds__(256, 2)
void attn2_k(const u16* __restrict__ Q, const u16* __restrict__ K,
             const u16* __restrict__ Vt, u16* __restrict__ O) {
  __shared__ u16 Ks[2][64 * 128];
  __shared__ u16 Vs[2][128 * 64];
  __shared__ u16 Plds[4][16 * 72];
  const int bid = blockIdx.x;                 // grid = 1024
  const int lb = (bid & 7) * 128 + (bid >> 3);
  const int bh = lb >> 4;
  const int mtile = lb & 15;
  const int b = bh >> 3, h = bh & 7;
  const int tid = threadIdx.x, lane = tid & 63, w = tid >> 6;
  const int l15 = lane & 15, l4 = lane >> 4;

  short8 qf[4];
  {
    const int qrow = b * 1024 + mtile * 64 + w * 16 + l15;
    const u16* qb = Q + ((size_t)qrow << 10) + h * 128;
    #pragma unroll
    for (int kk = 0; kk < 4; ++kk)
      qf[kk] = *(const short8*)(qb + kk * 32 + l4 * 8);
  }

  f32x4 o[8];
  #pragma unroll
  for (int db = 0; db < 8; ++db) o[db] = (f32x4){0.f, 0.f, 0.f, 0.f};
  float mrow[4], lrow[4];
  #pragma unroll
  for (int j = 0; j < 4; ++j) { mrow[j] = -1e30f; lrow[j] = 0.f; }
  const float scale = 0.08838834764831845f;

  auto stageKV = [&](int kt, int half) {
    #pragma unroll
    for (int j = 0; j < 4; ++j) {
      const int c = (j * 4 + w) * 64 + lane;
      const int r = c >> 4;
      const int coff = (((c & 15) ^ (r & 7)) << 3);
      const u16* gp = K + ((size_t)(b * 1024 + kt * 64 + r) << 10) + h * 128 + coff;
      gload16(gp, (void*)(Ks[half] + (j * 4 + w) * 512));
    }
    #pragma unroll
    for (int j = 0; j < 4; ++j) {
      const int c = (j * 4 + w) * 64 + lane;
      const int r = c >> 3;
      const int coff = (((c & 7) ^ (r & 7)) << 3);
      const u16* gp = Vt + ((size_t)((b * 8 + h) * 128 + r) << 10) + kt * 64 + coff;
      gload16(gp, (void*)(Vs[half] + (j * 4 + w) * 512));
    }
  };

  stageKV(0, 0);
  for (int kt = 0; kt < 16; ++kt) {
    const int cur = kt & 1;
    asm volatile("s_waitcnt vmcnt(0)" ::: "memory");
    __builtin_amdgcn_s_barrier();
    if (kt + 1 < 16) stageKV(kt + 1, cur ^ 1);

    const u16* ks_ = Ks[cur];
    const u16* vs_ = Vs[cur];
    f32x4 s[4];
    #pragma unroll
    for (int cb = 0; cb < 4; ++cb) {
      s[cb] = (f32x4){0.f, 0.f, 0.f, 0.f};
      #pragma unroll
      for (int kk = 0; kk < 4; ++kk) {
        const int col = (kk * 32 + l4 * 8) ^ ((l15 & 7) << 3);
        short8 bK = *(const short8*)(ks_ + (cb * 16 + l15) * 128 + col);
        __builtin_amdgcn_s_setprio(1);
        s[cb] = __builtin_amdgcn_mfma_f32_16x16x32_bf16(qf[kk], bK, s[cb], 0, 0, 0);
        __builtin_amdgcn_s_setprio(0);
      }
    }
    #pragma unroll
    for (int cb = 0; cb < 4; ++cb) {
      s[cb][0] *= scale; s[cb][1] *= scale; s[cb][2] *= scale; s[cb][3] *= scale;
    }
    #pragma unroll
    for (int j = 0; j < 4; ++j) {
      float mx = fmaxf(fmaxf(s[0][j], s[1][j]), fmaxf(s[2][j], s[3][j]));
      #pragma unroll
      for (int off = 8; off >= 1; off >>= 1)
        mx = fmaxf(mx, __shfl_xor(mx, off, 64));
      const float mn = fmaxf(mrow[j], mx);
      const float fac = __expf(mrow[j] - mn);
      mrow[j] = mn;
      float rs = 0.f;
      #pragma unroll
      for (int cb = 0; cb < 4; ++cb) {
        const float p = __expf(s[cb][j] - mn);
        s[cb][j] = p;
        rs += p;
      }
      #pragma unroll
      for (int off = 8; off >= 1; off >>= 1)
        rs += __shfl_xor(rs, off, 64);
      lrow[j] = lrow[j] * fac + rs;
      #pragma unroll
      for (int db = 0; db < 8; ++db) o[db][j] *= fac;
    }
    u16* pl = Plds[w];
    #pragma unroll
    for (int cb = 0; cb < 4; ++cb)
      #pragma unroll
      for (int j = 0; j < 4; ++j)
        pl[(l4 * 4 + j) * 72 + cb * 16 + l15] = f2bf(s[cb][j]);
    asm volatile("s_waitcnt lgkmcnt(0)" ::: "memory");
    __builtin_amdgcn_sched_barrier(0);
    short8 ap[2];
    #pragma unroll
    for (int ks2 = 0; ks2 < 2; ++ks2)
      ap[ks2] = *(const short8*)(pl + l15 * 72 + ks2 * 32 + l4 * 8);
    #pragma unroll
    for (int db = 0; db < 8; ++db) {
      #pragma unroll
      for (int ks2 = 0; ks2 < 2; ++ks2) {
        const int col = (ks2 * 32 + l4 * 8) ^ ((l15 & 7) << 3);
        short8 bV = *(const short8*)(vs_ + (db * 16 + l15) * 64 + col);
        __builtin_amdgcn_s_setprio(1);
        o[db] = __builtin_amdgcn_mfma_f32_16x16x32_bf16(ap[ks2], bV, o[db], 0, 0, 0);
        __builtin_amdgcn_s_setprio(0);
      }
    }
  }
  #pragma unroll
  for (int db = 0; db < 8; ++db) {
    #pragma unroll
    for (int j = 0; j < 4; ++j) {
      const int grow = b * 1024 + mtile * 64 + w * 16 + l4 * 4 + j;
      const int gcol = h * 128 + db * 16 + l15;
      O[((size_t)grow << 10) + gcol] = f2bf(o[db][j] / lrow[j]);
    }
  }
}

// ---------------- launch ----------------

extern "C" void kernel_launch(void* const* d_in, const int* in_sizes, int n_in,
                              void* d_out, int out_size, void* d_ws, size_t ws_size,
                              hipStream_t stream) {
  const float* x1     = (const float*)d_in[0];
  const float* x2     = (const float*)d_in[1];
  const float* conv_w = (const float*)d_in[2];
  const float* conv_b = (const float*)d_in[3];
  const float* wq     = (const float*)d_in[4];
  const float* wk     = (const float*)d_in[5];
  const float* wv     = (const float*)d_in[6];
  const float* proj_w = (const float*)d_in[7];
  const float* proj_b = (const float*)d_in[8];
  float* out = (float*)d_out;

  char* ws = (char*)d_ws;
  size_t off = 0;
  auto alloc = [&](size_t bytes) -> void* {
    void* p = ws + off;
    off += (bytes + 255) & ~(size_t)255;
    return p;
  };
  u16* x1b  = (u16*)alloc(8192ULL * 1024 * 2);
  u16* in_t_pad = (u16*)alloc((9248ULL + 96) * 2048 * 2);
  u16* Wp   = (u16*)alloc(9ULL * 2097152 * 2);
  u16* wqb  = (u16*)alloc(1048576ULL * 2);
  u16* wkb  = (u16*)alloc(1048576ULL * 2);
  u16* wvb  = (u16*)alloc(1048576ULL * 2);
  u16* pjb  = (u16*)alloc(1048576ULL * 2);
  u16* xc   = (u16*)alloc(8192ULL * 1024 * 2);
  u16* Qb   = (u16*)alloc(8192ULL * 1024 * 2);
  u16* Kb   = (u16*)alloc(8192ULL * 1024 * 2);
  u16* Vtb  = (u16*)alloc(8192ULL * 1024 * 2);
  u16* Ob   = (u16*)alloc(8192ULL * 1024 * 2);
  float* pConv = (float*)Qb;   // split-K f32 partials alias Qb..Ob

  // prep (border-only zeroing replaces the 38MB memset)
  border0_k<<<dim3(132, 8), 256, 0, stream>>>(in_t_pad);
  cast4_k<<<dim3(1024, 4), 256, 0, stream>>>(wq, wk, wv, proj_w, wqb, wkb, wvb, pjb);
  build_pad<<<dim3(32, 16, 8), 256, 0, stream>>>(x1, x2, in_t_pad, x1b);
  pack_wp<<<8192, 256, 0, stream>>>(conv_w, Wp);

  // conv: halo-reuse implicit GEMM (frozen), split-K x2
  conv9_k<<<256, 256, 0, stream>>>(in_t_pad, Wp, pConv);
  addc_k<<<dim3(16, 16, 8), 256, 0, stream>>>(pConv, conv_b, xc);
  // fused Q + K + V with conv9-class 256x256 structure (V via LDS transpose)
  qkv2_k<<<384, 256, 0, stream>>>(x1b, xc, wqb, wkb, wvb, Qb, Kb, Vtb);
  // attention (1D grid, KV-locality remap)
  attn2_k<<<1024, 256, 0, stream>>>(Qb, Kb, Vtb, Ob);
  // projection + bias + residual
  gemm3_k<GM_PROJ><<<256, 512, 0, stream>>>(Ob, pjb, nullptr, out, proj_b, x1, 1024, 3);
}